// Round 6
// baseline (411.470 us; speedup 1.0000x reference)
//
#include <hip/hip_runtime.h>
#include <hip/hip_bf16.h>

// Problem constants
#define NTOK 4096      // B*S
#define DIM  512       // D
#define DH   256       // D/2
#define NE   16        // experts
#define FF   2048      // F
#define CAP  8192      // per-expert list capacity
#define MAXTILES 80    // sum ceil(cnt_e/128) <= 79
#define TEMP_INV 2.0f  // 1/temperature

// out layout: [NTOK*DIM output][1 loss][NTOK*NE probs]
#define OUT_LOSS  (NTOK * DIM)
#define OUT_PROBS (NTOK * DIM + 1)

// ws layout (bytes). Temporal reuse:
//   H (4MB, dead after score) and G (10MB, written after) share [1MB..).
//   pairbuf (16MB, written by down) reuses Tup region (dead after up).
#define WS_CNT    0            // int[16]
#define WS_USAGE  64           // float[16]
#define WS_NTILES 128          // int
#define WS_DESC   256          // int2[80]
#define WS_WTS    1024         // float[2*NTOK]
#define WS_LISTS  36864        // int[16*CAP] (512KB)
#define WS_H      (1ull<<20)   // fp32 [4096][256] = 4MB
#define WS_G      (1ull<<20)   // bf16 [80][8][128][64] = 10MB (swizzled granules)
#define WS_TUP    (16ull<<20)  // bf16 [16*8][2048][64] = 32MB (swizzled granules)
#define WS_PAIR   (16ull<<20)  // fp32 [8192][512] = 16MB (after Tup dead)
#define WS_TDN    (48ull<<20)  // bf16 [16*32][512][64] = 32MB (swizzled granules)
#define WS_HID    (80ull<<20)  // bf16 [80*32][128][64] = 40MB (swizzled granules)

typedef __attribute__((ext_vector_type(8))) short bf16x8;           // MFMA A/B frag
typedef __attribute__((ext_vector_type(8))) unsigned short u16x8;   // 8 bf16 storage
typedef __attribute__((ext_vector_type(4))) float f32x4;            // MFMA C/D frag

__device__ __forceinline__ unsigned short f2bf(float f) {  // RNE f32->bf16
  union { float f; unsigned u; } c; c.f = f;
  return (unsigned short)((c.u + 0x7FFFu + ((c.u >> 16) & 1u)) >> 16);
}
__device__ __forceinline__ float gc(const float4& v, int c) {
  return c == 0 ? v.x : c == 1 ? v.y : c == 2 ? v.z : v.w;
}

// async global->LDS, 16B per lane. LDS dest = wave-uniform base + lane*16.
#define GLOAD16(gp, lp) __builtin_amdgcn_global_load_lds( \
    (const __attribute__((address_space(1))) void*)(gp), \
    (__attribute__((address_space(3))) void*)(lp), 16, 0, 0)

// =================== router: h = relu(x@w1+b1) -> H ===================
// 512 blocks x 64 threads; [64tok][32col] per block, 8x4 per thread.
__launch_bounds__(64)
__global__ void router_kernel(const float* __restrict__ x,
                              const float* __restrict__ w1,
                              const float* __restrict__ b1,
                              float* __restrict__ H) {
  __shared__ __align__(16) float As[32 * 72];  // [32k][64tok pad72]
  __shared__ __align__(16) float Bs[32 * 40];  // [32k][32col pad40]
  int bx = blockIdx.x, tid = threadIdx.x;
  int tok0 = (bx >> 3) * 64, n0 = (bx & 7) * 32;
  int ty = tid >> 3, tx = tid & 7;             // 8x8 threads; tile 8tok x 4col
  float acc[8][4];
#pragma unroll
  for (int r = 0; r < 8; ++r)
#pragma unroll
    for (int c = 0; c < 4; ++c) acc[r][c] = 0.f;

  for (int kc = 0; kc < 16; ++kc) {
    int k0 = kc * 32;
    {
      const float* xp = x + (size_t)(tok0 + tid) * DIM + k0;
#pragma unroll
      for (int q = 0; q < 8; ++q) {
        float4 v = *(const float4*)(xp + q * 4);
        As[(q * 4 + 0) * 72 + tid] = v.x;
        As[(q * 4 + 1) * 72 + tid] = v.y;
        As[(q * 4 + 2) * 72 + tid] = v.z;
        As[(q * 4 + 3) * 72 + tid] = v.w;
      }
    }
    {
      int kk = tid >> 1, ns = (tid & 1) * 16;
#pragma unroll
      for (int j = 0; j < 4; ++j)
        *(float4*)&Bs[kk * 40 + ns + j * 4] =
            *(const float4*)(w1 + (size_t)(k0 + kk) * DH + n0 + ns + j * 4);
    }
    __syncthreads();
#pragma unroll 8
    for (int k = 0; k < 32; ++k) {
      float4 a0 = *(const float4*)&As[k * 72 + ty * 8];
      float4 a1 = *(const float4*)&As[k * 72 + ty * 8 + 4];
      float4 b  = *(const float4*)&Bs[k * 40 + tx * 4];
#pragma unroll
      for (int c = 0; c < 4; ++c) {
        float bv = (c == 0) ? b.x : (c == 1) ? b.y : (c == 2) ? b.z : b.w;
        acc[0][c] = fmaf(a0.x, bv, acc[0][c]);
        acc[1][c] = fmaf(a0.y, bv, acc[1][c]);
        acc[2][c] = fmaf(a0.z, bv, acc[2][c]);
        acc[3][c] = fmaf(a0.w, bv, acc[3][c]);
        acc[4][c] = fmaf(a1.x, bv, acc[4][c]);
        acc[5][c] = fmaf(a1.y, bv, acc[5][c]);
        acc[6][c] = fmaf(a1.z, bv, acc[6][c]);
        acc[7][c] = fmaf(a1.w, bv, acc[7][c]);
      }
    }
    __syncthreads();
  }
  float4 bb = *(const float4*)(b1 + n0 + tx * 4);
#pragma unroll
  for (int r = 0; r < 8; ++r) {
    float4 o;
    o.x = fmaxf(acc[r][0] + bb.x, 0.f);
    o.y = fmaxf(acc[r][1] + bb.y, 0.f);
    o.z = fmaxf(acc[r][2] + bb.z, 0.f);
    o.w = fmaxf(acc[r][3] + bb.w, 0.f);
    *(float4*)(H + (size_t)(tok0 + ty * 8 + r) * DH + n0 + tx * 4) = o;
  }
}

// =================== convert: weights fp32 [k][n] -> bf16 [n][64k], swizzled; no LDS ===================
// 512 blocks x 256 threads. Thread owns 4 output rows; vector float4 loads.
// bx < 256:   up_w  -> Tup [e*8+kc][2048f][64k]
// bx >= 256: down_w -> Tdn [e*32+kc][512d][64k]
__launch_bounds__(256)
__global__ void convert_kernel(const float* __restrict__ up_w,
                               const float* __restrict__ down_w,
                               unsigned short* __restrict__ Tup,
                               unsigned short* __restrict__ Tdn) {
  int bx = blockIdx.x, tid = threadIdx.x;
  const float* src; unsigned short* dst; int stride, f;
  if (bx < 256) {
    int e = bx >> 4, kc = (bx >> 1) & 7, half = bx & 1;
    f = (half * 256 + tid) * 4;
    src = up_w + (size_t)e * DIM * FF + (size_t)(kc * 64) * FF + f;
    dst = Tup + ((size_t)(e * 8 + kc) * FF + f) * 64;
    stride = FF;
  } else {
    int u = bx - 256;
    int e = u >> 4, kcp = u & 15;
    int kc = kcp * 2 + (tid >> 7);
    f = (tid & 127) * 4;
    src = down_w + (size_t)e * FF * DIM + (size_t)(kc * 64) * DIM + f;
    dst = Tdn + ((size_t)(e * 32 + kc) * DIM + f) * 64;
    stride = DIM;
  }
#pragma unroll
  for (int g = 0; g < 8; ++g) {
    float4 v[8];
#pragma unroll
    for (int j = 0; j < 8; ++j)
      v[j] = *(const float4*)(src + (size_t)(g * 8 + j) * stride);
#pragma unroll
    for (int c = 0; c < 4; ++c) {
      u16x8 pk;
#pragma unroll
      for (int j = 0; j < 8; ++j) pk[j] = f2bf(gc(v[j], c));
      int fr = f + c;
      *(u16x8*)(dst + (size_t)c * 64 + ((g ^ (fr & 7)) << 3)) = pk;
    }
  }
}

// =================== score: softmax + top2 + lists (per 16 tokens) ===================
__launch_bounds__(256)
__global__ void score_kernel(const float* __restrict__ H,
                             const float* __restrict__ w2,
                             const float* __restrict__ b2,
                             float* __restrict__ out,
                             int* __restrict__ cnt,
                             float* __restrict__ usage,
                             float* __restrict__ wts,
                             int* __restrict__ lists) {
  __shared__ __align__(16) float hs[16][260];
  __shared__ __align__(16) float w2t[16][260];
  __shared__ float ps[16][NE];
  __shared__ float us[4][NE];
  int tid = threadIdx.x;
  int tok0 = blockIdx.x * 16;
  {
    int r = tid >> 4, seg = tid & 15;
    const float* hp = H + (size_t)(tok0 + r) * DH + seg * 16;
    *(float4*)&hs[r][seg * 16 + 0]  = *(const float4*)(hp + 0);
    *(float4*)&hs[r][seg * 16 + 4]  = *(const float4*)(hp + 4);
    *(float4*)&hs[r][seg * 16 + 8]  = *(const float4*)(hp + 8);
    *(float4*)&hs[r][seg * 16 + 12] = *(const float4*)(hp + 12);
  }
  {
    float4 a = *(const float4*)(w2 + (size_t)tid * 16 + 0);
    float4 b = *(const float4*)(w2 + (size_t)tid * 16 + 4);
    float4 c = *(const float4*)(w2 + (size_t)tid * 16 + 8);
    float4 d = *(const float4*)(w2 + (size_t)tid * 16 + 12);
    w2t[0][tid] = a.x;  w2t[1][tid] = a.y;  w2t[2][tid] = a.z;  w2t[3][tid] = a.w;
    w2t[4][tid] = b.x;  w2t[5][tid] = b.y;  w2t[6][tid] = b.z;  w2t[7][tid] = b.w;
    w2t[8][tid] = c.x;  w2t[9][tid] = c.y;  w2t[10][tid] = c.z; w2t[11][tid] = c.w;
    w2t[12][tid] = d.x; w2t[13][tid] = d.y; w2t[14][tid] = d.z; w2t[15][tid] = d.w;
  }
  __syncthreads();
  int t = tid >> 4, e = tid & 15;
  float s = b2[e];
#pragma unroll 4
  for (int j4 = 0; j4 < 64; ++j4) {
    float4 hv = *(const float4*)&hs[t][j4 * 4];
    float4 wv = *(const float4*)&w2t[e][j4 * 4];
    s = fmaf(hv.x, wv.x, fmaf(hv.y, wv.y, fmaf(hv.z, wv.z, fmaf(hv.w, wv.w, s))));
  }
  s *= TEMP_INV;
  float m = s;
#pragma unroll
  for (int d = 1; d < 16; d <<= 1) m = fmaxf(m, __shfl_xor(m, d));
  float p = expf(s - m);
  float sum = p;
#pragma unroll
  for (int d = 1; d < 16; d <<= 1) sum += __shfl_xor(sum, d);
  float prob = p / sum;
  out[OUT_PROBS + (size_t)(tok0 + t) * NE + e] = prob;
  ps[t][e] = prob;
  float v = prob;
  v += __shfl_xor(v, 16);
  v += __shfl_xor(v, 32);
  if ((tid & 63) < 16) us[tid >> 6][e] = v;
  __syncthreads();
  if (tid < 16) atomicAdd(&usage[tid], us[0][tid] + us[1][tid] + us[2][tid] + us[3][tid]);

  if (tid < 16) {
    int tt = tid;
    float v1 = -1.f; int i1 = 0;
    for (int ee = 0; ee < NE; ++ee) { float pv = ps[tt][ee]; if (pv > v1) { v1 = pv; i1 = ee; } }
    float v2 = -1.f; int i2 = 0;
    for (int ee = 0; ee < NE; ++ee) { if (ee == i1) continue; float pv = ps[tt][ee]; if (pv > v2) { v2 = pv; i2 = ee; } }
    float mm = fmaxf(v1, v2);
    float e0 = expf(v1 - mm), e1 = expf(v2 - mm);
    float rs = 1.f / (e0 + e1);
    int gt = tok0 + tt;
    wts[2 * gt]     = e0 * rs;
    wts[2 * gt + 1] = e1 * rs;
    int p1 = atomicAdd(&cnt[i1], 1);
    lists[i1 * CAP + p1] = 2 * gt;
    int p2 = atomicAdd(&cnt[i2], 1);
    lists[i2 * CAP + p2] = 2 * gt + 1;
  }
}

// =================== sched: tile descriptors + load-balance loss ===================
__global__ void sched_kernel(const int* __restrict__ cnt,
                             const float* __restrict__ usage,
                             int* __restrict__ ntiles,
                             int2* __restrict__ desc,
                             float* __restrict__ out_loss) {
  int lane = threadIdx.x;
  int e = lane & 15;
  int c = (lane < 16) ? cnt[e] : 0;
  int tl = (c + 127) >> 7;
  int v = tl;
#pragma unroll
  for (int d = 1; d < 16; d <<= 1) {
    int u = __shfl_up(v, d);
    if (lane >= d) v += u;
  }
  int excl = v - tl;
  int tot = __shfl(v, 15);
  if (lane == 0) *ntiles = tot;
  if (lane < 16) {
    for (int i = 0; i < tl; ++i) desc[excl + i] = make_int2(e, i << 7);
    float d0 = usage[e] * (1.f / 4096.f) - (1.f / 16.f);
    float ls = d0 * d0;
#pragma unroll
    for (int d = 1; d < 16; d <<= 1) ls += __shfl_xor(ls, d);
    if (lane == 0) *out_loss = ls * (1.f / 16.f);
  }
}

// =================== gather: build A bf16 chunk-major [ty][kc8][128][64], swizzled ===================
__launch_bounds__(256)
__global__ void gather_kernel(const float* __restrict__ x,
                              const int* __restrict__ cnt,
                              const int* __restrict__ ntiles,
                              const int2* __restrict__ desc,
                              const int* __restrict__ lists,
                              unsigned short* __restrict__ G) {
  int ty = blockIdx.x;
  if (ty >= *ntiles) return;
  int2 dd = desc[ty];
  int e = dd.x, i0 = dd.y;
  int cntE = cnt[e];
  int tid = threadIdx.x, r = tid >> 1, h = tid & 1;
  int aidx = i0 + r;
  bool valid = aidx < cntE;
  int slot = valid ? lists[e * CAP + aidx] : 0;
  const float* xrow = x + (size_t)(slot >> 1) * DIM;
  int chunk = blockIdx.y * 2 + h;
  unsigned short* dst = G + (size_t)ty * 65536 + (size_t)chunk * 8192 + r * 64;
  int sx = r & 7;
#pragma unroll
  for (int j = 0; j < 8; ++j) {
    u16x8 pk;
    if (valid) {
      float4 u = *(const float4*)(xrow + chunk * 64 + j * 8);
      float4 w = *(const float4*)(xrow + chunk * 64 + j * 8 + 4);
      pk[0] = f2bf(u.x); pk[1] = f2bf(u.y); pk[2] = f2bf(u.z); pk[3] = f2bf(u.w);
      pk[4] = f2bf(w.x); pk[5] = f2bf(w.y); pk[6] = f2bf(w.z); pk[7] = f2bf(w.w);
    } else {
      pk = u16x8{0, 0, 0, 0, 0, 0, 0, 0};
    }
    *(u16x8*)(dst + ((j ^ sx) << 3)) = pk;
  }
}

// =================== up GEMM: G @ Tup -> gelu -> hid (bf16, swizzled granules) ===================
// BM=128 BN=128 BK=64, 4 waves (2x2), double-buffered global_load_lds, 2-phase.
// 1D grid (16*MAXTILES), XCD-chunked so all 16 f-blocks of a ty share an XCD.
__launch_bounds__(256)
__global__ void up_kernel(const unsigned short* __restrict__ G,
                          const unsigned short* __restrict__ Tup,
                          const float* __restrict__ up_b,
                          const int* __restrict__ ntiles,
                          const int2* __restrict__ desc,
                          unsigned short* __restrict__ hid) {
  int lid = (blockIdx.x & 7) * (MAXTILES * 16 / 8) + (blockIdx.x >> 3);
  int ty = lid >> 4, fb = lid & 15;
  if (ty >= *ntiles) return;
  int e = desc[ty].x;
  int f0 = fb * 128;
  __shared__ __align__(16) unsigned short smem[32768];   // 64KB: A0 A1 B0 B1 (8192 each)
  int tid = threadIdx.x, lane = tid & 63, wid = tid >> 6;
  const unsigned short* Asrc = G + (size_t)ty * 65536;                    // + kc*8192
  const unsigned short* Bsrc = Tup + ((size_t)(e * 8) * FF + f0) * 64;    // + kc*FF*64

  int wr = wid >> 1, wc = wid & 1, ln15 = lane & 15, lq = lane >> 4;
  f32x4 acc[4][4];
#pragma unroll
  for (int i = 0; i < 4; ++i)
#pragma unroll
    for (int j = 0; j < 4; ++j) acc[i][j] = f32x4{0.f, 0.f, 0.f, 0.f};

#define UP_STAGE(b, kc) do {                                          \
    const unsigned short* a_ = Asrc + (size_t)(kc) * 8192;            \
    const unsigned short* b_ = Bsrc + (size_t)(kc) * FF * 64;         \
    unsigned short* al_ = smem + (b) * 8192;                          \
    unsigned short* bl_ = smem + 16384 + (b) * 8192;                  \
    _Pragma("unroll")                                                 \
    for (int i_ = 0; i_ < 4; ++i_) {                                  \
      int off_ = (wid * 4 + i_) * 512;                                \
      GLOAD16(a_ + off_ + lane * 8, al_ + off_ + lane * 8);           \
      GLOAD16(b_ + off_ + lane * 8, bl_ + off_ + lane * 8);           \
    }                                                                 \
  } while (0)

  UP_STAGE(0, 0);
  asm volatile("s_waitcnt vmcnt(0)" ::: "memory");
  __syncthreads();
  int cur = 0;
  for (int kc = 0; kc < 8; ++kc) {
    if (kc < 7) UP_STAGE(cur ^ 1, kc + 1);
    const unsigned short* As = smem + cur * 8192;
    const unsigned short* Bs = smem + 16384 + cur * 8192;
#pragma unroll
    for (int ksub = 0; ksub < 2; ++ksub) {
      bf16x8 a[4], b[4];
      int g = (ksub << 2) + lq;
      int sw = (g ^ (ln15 & 7)) << 3;   // XOR-swizzled granule slot
#pragma unroll
      for (int mi = 0; mi < 4; ++mi)
        a[mi] = *(const bf16x8*)(As + ((wr << 6) + (mi << 4) + ln15) * 64 + sw);
#pragma unroll
      for (int ni = 0; ni < 4; ++ni)
        b[ni] = *(const bf16x8*)(Bs + ((wc << 6) + (ni << 4) + ln15) * 64 + sw);
#pragma unroll
      for (int mi = 0; mi < 4; ++mi)
#pragma unroll
        for (int ni = 0; ni < 4; ++ni)
          acc[mi][ni] = __builtin_amdgcn_mfma_f32_16x16x32_bf16(a[mi], b[ni], acc[mi][ni], 0, 0, 0);
    }
    asm volatile("s_waitcnt vmcnt(0)" ::: "memory");
    __syncthreads();
    cur ^= 1;
  }
  // epilogue: bias + exact gelu -> LDS transpose -> vectorized swizzled hid stores
  unsigned short* Cs = smem;  // [128][136] u16 = 34.8KB (reuses A/B buffers)
#pragma unroll
  for (int mi = 0; mi < 4; ++mi) {
#pragma unroll
    for (int ni = 0; ni < 4; ++ni) {
      int col = (wc << 6) + (ni << 4) + ln15;
      float bias = up_b[e * FF + f0 + col];
#pragma unroll
      for (int q = 0; q < 4; ++q) {
        int row = (wr << 6) + (mi << 4) + (lq << 2) + q;
        float vv = acc[mi][ni][q] + bias;
        float gl = 0.5f * vv * (1.f + erff(vv * 0.70710678118f));
        Cs[row * 136 + col] = f2bf(gl);
      }
    }
  }
  __syncthreads();
#pragma unroll
  for (int i = 0; i < 8; ++i) {
    int seg = tid + i * 256;
    int row = seg >> 4, c16 = seg & 15;
    int chunk = ty * 32 + (f0 >> 6) + (c16 >> 3);
    int slot = (c16 & 7) ^ (row & 7);
    u16x8 v = *(const u16x8*)(Cs + row * 136 + c16 * 8);
    *(u16x8*)(hid + ((size_t)chunk * 128 + row) * 64 + (slot << 3)) = v;
  }
#undef UP_STAGE
}

// =================== down GEMM: hid @ Tdn -> pairbuf (fp32 scatter) ===================
// BM=128 BN=128 BK=64, 4 waves (2x2), 32 k-chunks, 2-phase.
// 1D grid (4*MAXTILES), XCD-chunked so all 4 n-blocks of a ty share an XCD.
__launch_bounds__(256)
__global__ void down_kernel(const unsigned short* __restrict__ hid,
                            const unsigned short* __restrict__ Tdn,
                            const float* __restrict__ down_b,
                            const int* __restrict__ cnt,
                            const int* __restrict__ ntiles,
                            const int2* __restrict__ desc,
                            const int* __restrict__ lists,
                            float* __restrict__ pairbuf) {
  int lid = (blockIdx.x & 7) * (MAXTILES * 4 / 8) + (blockIdx.x >> 3);
  int ty = lid >> 2, nb = lid & 3;
  if (ty >= *ntiles) return;
  int2 dd = desc[ty];
  int e = dd.x, i0 = dd.y;
  int cntE = cnt[e];
  int n0 = nb * 128;
  __shared__ __align__(16) unsigned short smem[32768];   // 64KB: A0 A1 B0 B1 (8192 each)
  int tid = threadIdx.x, lane = tid & 63, wid = tid >> 6;
  const unsigned short* Asrc = hid + (size_t)ty * 32 * 8192;              // + kc*8192
  const unsigned short* Bsrc = Tdn + ((size_t)(e * 32) * DIM + n0) * 64;  // + kc*DIM*64

  int wr = wid >> 1, wc = wid & 1, ln15 = lane & 15, lq = lane >> 4;
  f32x4 acc[4][4];
#pragma unroll
  for (int i = 0; i < 4; ++i)
#pragma unroll
    for (int j = 0; j < 4; ++j) acc[i][j] = f32x4{0.f, 0.f, 0.f, 0.f};

#define DN_STAGE(b, kc) do {                                          \
    const unsigned short* a_ = Asrc + (size_t)(kc) * 8192;            \
    const unsigned short* b_ = Bsrc + (size_t)(kc) * DIM * 64;        \
    unsigned short* al_ = smem + (b) * 8192;                          \
    unsigned short* bl_ = smem + 16384 + (b) * 8192;                  \
    _Pragma("unroll")                                                 \
    for (int i_ = 0; i_ < 4; ++i_) {                                  \
      int off_ = (wid * 4 + i_) * 512;                                \
      GLOAD16(a_ + off_ + lane * 8, al_ + off_ + lane * 8);           \
      GLOAD16(b_ + off_ + lane * 8, bl_ + off_ + lane * 8);           \
    }                                                                 \
  } while (0)

  DN_STAGE(0, 0);
  asm volatile("s_waitcnt vmcnt(0)" ::: "memory");
  __syncthreads();
  int cur = 0;
  for (int kc = 0; kc < 32; ++kc) {
    if (kc < 31) DN_STAGE(cur ^ 1, kc + 1);
    const unsigned short* As = smem + cur * 8192;
    const unsigned short* Bs = smem + 16384 + cur * 8192;
#pragma unroll
    for (int ksub = 0; ksub < 2; ++ksub) {
      bf16x8 a[4], b[4];
      int g = (ksub << 2) + lq;
      int sw = (g ^ (ln15 & 7)) << 3;
#pragma unroll
      for (int mi = 0; mi < 4; ++mi)
        a[mi] = *(const bf16x8*)(As + ((wr << 6) + (mi << 4) + ln15) * 64 + sw);
#pragma unroll
      for (int ni = 0; ni < 4; ++ni)
        b[ni] = *(const bf16x8*)(Bs + ((wc << 6) + (ni << 4) + ln15) * 64 + sw);
#pragma unroll
      for (int mi = 0; mi < 4; ++mi)
#pragma unroll
        for (int ni = 0; ni < 4; ++ni)
          acc[mi][ni] = __builtin_amdgcn_mfma_f32_16x16x32_bf16(a[mi], b[ni], acc[mi][ni], 0, 0, 0);
    }
    asm volatile("s_waitcnt vmcnt(0)" ::: "memory");
    __syncthreads();
    cur ^= 1;
  }
  // epilogue: bias + scatter rows via lists (64B-coalesced per quarter-wave)
#pragma unroll
  for (int mi = 0; mi < 4; ++mi) {
    int row = (wr << 6) + (mi << 4) + (lq << 2);
#pragma unroll
    for (int ni = 0; ni < 4; ++ni) {
      int col = n0 + (wc << 6) + (ni << 4) + ln15;
      float bias = down_b[e * DIM + col];
#pragma unroll
      for (int q = 0; q < 4; ++q) {
        int idx = i0 + row + q;
        if (idx < cntE) {
          int slot = lists[e * CAP + idx];
          pairbuf[(size_t)slot * DIM + col] = acc[mi][ni][q] + bias;
        }
      }
    }
  }
#undef DN_STAGE
}

// =================== combine: out[t] = w0*pair[2t] + w1*pair[2t+1] ===================
__launch_bounds__(256)
__global__ void combine_kernel(const float* __restrict__ pairbuf,
                               const float* __restrict__ wts,
                               float* __restrict__ out) {
  int idx = blockIdx.x * 256 + threadIdx.x;   // one float4 of output
  int t = idx >> 7, d4 = (idx & 127) << 2;
  float w0 = wts[2 * t], w1 = wts[2 * t + 1];
  float4 a = *(const float4*)(pairbuf + (size_t)(2 * t) * DIM + d4);
  float4 b = *(const float4*)(pairbuf + (size_t)(2 * t + 1) * DIM + d4);
  float4 r;
  r.x = w0 * a.x + w1 * b.x; r.y = w0 * a.y + w1 * b.y;
  r.z = w0 * a.z + w1 * b.z; r.w = w0 * a.w + w1 * b.w;
  *(float4*)(out + (size_t)t * DIM + d4) = r;
}

extern "C" void kernel_launch(void* const* d_in, const int* in_sizes, int n_in,
                              void* d_out, int out_size, void* d_ws, size_t ws_size,
                              hipStream_t stream) {
  (void)in_sizes; (void)n_in; (void)out_size; (void)ws_size;
  const float* x   = (const float*)d_in[0];
  const float* gw1 = (const float*)d_in[1];
  const float* gb1 = (const float*)d_in[2];
  const float* gw2 = (const float*)d_in[3];
  const float* gb2 = (const float*)d_in[4];
  const float* uw  = (const float*)d_in[5];
  const float* ub  = (const float*)d_in[6];
  const float* dw  = (const float*)d_in[7];
  const float* db  = (const float*)d_in[8];
  float* out = (float*)d_out;
  char* ws = (char*)d_ws;

  int*   cnt     = (int*)(ws + WS_CNT);
  float* usage   = (float*)(ws + WS_USAGE);
  int*   ntiles  = (int*)(ws + WS_NTILES);
  int2*  desc    = (int2*)(ws + WS_DESC);
  float* wts     = (float*)(ws + WS_WTS);
  int*   lists   = (int*)(ws + WS_LISTS);
  float* H       = (float*)(ws + WS_H);
  unsigned short* G   = (unsigned short*)(ws + WS_G);
  unsigned short* Tup = (unsigned short*)(ws + WS_TUP);
  unsigned short* Tdn = (unsigned short*)(ws + WS_TDN);
  unsigned short* hid = (unsigned short*)(ws + WS_HID);
  float* pairbuf = (float*)(ws + WS_PAIR);

  hipMemsetAsync(d_ws, 0, 1024, stream);  // zero cnt/usage/ntiles
  router_kernel<<<512, 64, 0, stream>>>(x, gw1, gb1, H);
  convert_kernel<<<512, 256, 0, stream>>>(uw, dw, Tup, Tdn);
  score_kernel<<<NTOK / 16, 256, 0, stream>>>(H, gw2, gb2, out, cnt, usage, wts, lists);
  sched_kernel<<<1, 64, 0, stream>>>(cnt, usage, ntiles, desc, out + OUT_LOSS);
  gather_kernel<<<dim3(MAXTILES, 4), 256, 0, stream>>>(x, cnt, ntiles, desc, lists, G);
  up_kernel<<<16 * MAXTILES, 256, 0, stream>>>(G, Tup, ub, ntiles, desc, hid);
  down_kernel<<<4 * MAXTILES, 256, 0, stream>>>(hid, Tdn, db, cnt, ntiles, desc, lists, pairbuf);
  combine_kernel<<<NTOK * DIM / 4 / 256, 256, 0, stream>>>(pairbuf, wts, out);
}

// Round 7
// 372.433 us; speedup vs baseline: 1.1048x; 1.1048x over previous
//
#include <hip/hip_runtime.h>
#include <hip/hip_bf16.h>

// Problem constants
#define NTOK 4096      // B*S
#define DIM  512       // D
#define DH   256       // D/2
#define NE   16        // experts
#define FF   2048      // F
#define CAP  8192      // per-expert list capacity
#define MAXTILES 80    // sum ceil(cnt_e/128) <= 79
#define TEMP_INV 2.0f  // 1/temperature

// out layout: [NTOK*DIM output][1 loss][NTOK*NE probs]
#define OUT_LOSS  (NTOK * DIM)
#define OUT_PROBS (NTOK * DIM + 1)

// ws layout (bytes)
#define WS_CNT    0            // int[16]
#define WS_USAGE  64           // float[16]
#define WS_NTILES 128          // int
#define WS_DESC   256          // int2[80]
#define WS_WTS    1024         // float[2*NTOK]
#define WS_LISTS  36864        // int[16*CAP] (512KB)
#define WS_H      (1ull<<20)   // fp32 [4096][256] = 4MB
#define WS_G      (1ull<<20)   // bf16 [80][8][128][64] = 10MB (swizzled granules)
#define WS_TUP    (16ull<<20)  // bf16 [16*8][2048][64] = 32MB (swizzled granules)
#define WS_PAIR   (16ull<<20)  // fp32 [8192][512] = 16MB (after Tup dead)
#define WS_TDN    (48ull<<20)  // bf16 [16*32][512][64] = 32MB (swizzled granules)
#define WS_HID    (80ull<<20)  // bf16 [80*32][128][64] = 40MB (swizzled granules)

typedef __attribute__((ext_vector_type(8))) short bf16x8;           // MFMA A/B frag
typedef __attribute__((ext_vector_type(8))) unsigned short u16x8;   // 8 bf16 storage
typedef __attribute__((ext_vector_type(4))) float f32x4;            // MFMA C/D frag

__device__ __forceinline__ unsigned short f2bf(float f) {  // RNE f32->bf16
  union { float f; unsigned u; } c; c.f = f;
  return (unsigned short)((c.u + 0x7FFFu + ((c.u >> 16) & 1u)) >> 16);
}
__device__ __forceinline__ float gc(const float4& v, int c) {
  return c == 0 ? v.x : c == 1 ? v.y : c == 2 ? v.z : v.w;
}

// async global->LDS, 16B per lane. LDS dest = wave-uniform base + lane*16.
#define GLOAD16(gp, lp) __builtin_amdgcn_global_load_lds( \
    (const __attribute__((address_space(1))) void*)(gp), \
    (__attribute__((address_space(3))) void*)(lp), 16, 0, 0)

// =================== prep: weight convert (2048 blk) + router-h GEMM (128 blk) ===================
// 256-thread blocks, 41984B LDS.
// bx < 1024:          up_w [e][512k][2048f] -> Tup [e*8+kc][2048f][64k] swizzled (64k x 256f slabs)
// bx in [1024,2048): down_w [e][2048k][512d] -> Tdn [e*32+kc][512d][64k] swizzled
// bx >= 2048: router h = relu(x@w1+b1) -> H; [256tok][32col] per block (64tok/wave)
__launch_bounds__(256)
__global__ void prep_kernel(const float* __restrict__ x,
                            const float* __restrict__ w1,
                            const float* __restrict__ b1,
                            const float* __restrict__ up_w,
                            const float* __restrict__ down_w,
                            float* __restrict__ H,
                            unsigned short* __restrict__ Tup,
                            unsigned short* __restrict__ Tdn) {
  __shared__ __align__(16) char smem[41984];
  int bx = blockIdx.x, tid = threadIdx.x;

  if (bx < 2048) {
    // ---- LDS-transpose convert: slab [64k][256n] fp32 -> 256 swizzled bf16 rows [n][64k] ----
    const float* src; unsigned short* dst; int stride;
    if (bx < 1024) {
      int e = bx >> 6, kc = (bx >> 3) & 7, nb = bx & 7;
      src = up_w + (size_t)e * DIM * FF + (size_t)(kc * 64) * FF + nb * 256;
      dst = Tup + ((size_t)(e * 8 + kc) * FF + nb * 256) * 64;
      stride = FF;
    } else {
      int u = bx - 1024;
      int e = u >> 6, kc = (u >> 1) & 31, nb = u & 1;
      src = down_w + (size_t)e * FF * DIM + (size_t)(kc * 64) * DIM + nb * 256;
      dst = Tdn + ((size_t)(e * 32 + kc) * DIM + nb * 256) * 64;
      stride = DIM;
    }
    unsigned short* L = (unsigned short*)smem;   // [256n][72 (64k + pad)]
    int r = tid & 63, cg = tid >> 6;             // r = k-row, cg = 64-col group
    const float* sp = src + (size_t)r * stride + cg * 64;
#pragma unroll
    for (int j = 0; j < 16; ++j) {
      float4 v = *(const float4*)(sp + j * 4);
      int nl = cg * 64 + j * 4;
      L[(nl + 0) * 72 + r] = f2bf(v.x);
      L[(nl + 1) * 72 + r] = f2bf(v.y);
      L[(nl + 2) * 72 + r] = f2bf(v.z);
      L[(nl + 3) * 72 + r] = f2bf(v.w);
    }
    __syncthreads();
    int w = tid >> 6, lane = tid & 63, sub = lane >> 3, g = lane & 7;
#pragma unroll
    for (int i = 0; i < 8; ++i) {
      int nl = w * 64 + i * 8 + sub;
      u16x8 v = *(const u16x8*)(L + nl * 72 + g * 8);
      *(u16x8*)(dst + (size_t)nl * 64 + ((g ^ (nl & 7)) << 3)) = v;
    }
  } else {
    // ---- router h GEMM: [256tok][32col]; wave w owns tok strip w*64 ----
    int rb = bx - 2048;
    int tok0 = (rb >> 3) * 256, n0 = (rb & 7) * 32;
    int w = tid >> 6, lane = tid & 63;
    float* Af = (float*)smem + w * (32 * 72);    // per-wave [32k][64tok pad72]
    float* Bs = (float*)(smem + 36864);          // [32k][32col pad40]
    int ty = lane >> 3, tx = lane & 7;
    float acc[8][4];
#pragma unroll
    for (int r = 0; r < 8; ++r)
#pragma unroll
      for (int c = 0; c < 4; ++c) acc[r][c] = 0.f;

    for (int kc = 0; kc < 16; ++kc) {
      int k0 = kc * 32;
      {
        const float* xp = x + (size_t)(tok0 + w * 64 + lane) * DIM + k0;
#pragma unroll
        for (int q = 0; q < 8; ++q) {
          float4 v = *(const float4*)(xp + q * 4);
          Af[(q * 4 + 0) * 72 + lane] = v.x;
          Af[(q * 4 + 1) * 72 + lane] = v.y;
          Af[(q * 4 + 2) * 72 + lane] = v.z;
          Af[(q * 4 + 3) * 72 + lane] = v.w;
        }
      }
      {
        int kk = tid >> 3, ns = (tid & 7) * 4;
        *(float4*)&Bs[kk * 40 + ns] = *(const float4*)(w1 + (size_t)(k0 + kk) * DH + n0 + ns);
      }
      __syncthreads();
#pragma unroll 8
      for (int k = 0; k < 32; ++k) {
        float4 a0 = *(const float4*)&Af[k * 72 + ty * 8];
        float4 a1 = *(const float4*)&Af[k * 72 + ty * 8 + 4];
        float4 b  = *(const float4*)&Bs[k * 40 + tx * 4];
#pragma unroll
        for (int c = 0; c < 4; ++c) {
          float bv = (c == 0) ? b.x : (c == 1) ? b.y : (c == 2) ? b.z : b.w;
          acc[0][c] = fmaf(a0.x, bv, acc[0][c]);
          acc[1][c] = fmaf(a0.y, bv, acc[1][c]);
          acc[2][c] = fmaf(a0.z, bv, acc[2][c]);
          acc[3][c] = fmaf(a0.w, bv, acc[3][c]);
          acc[4][c] = fmaf(a1.x, bv, acc[4][c]);
          acc[5][c] = fmaf(a1.y, bv, acc[5][c]);
          acc[6][c] = fmaf(a1.z, bv, acc[6][c]);
          acc[7][c] = fmaf(a1.w, bv, acc[7][c]);
        }
      }
      __syncthreads();
    }
    float4 bb = *(const float4*)(b1 + n0 + tx * 4);
#pragma unroll
    for (int r = 0; r < 8; ++r) {
      float4 o;
      o.x = fmaxf(acc[r][0] + bb.x, 0.f);
      o.y = fmaxf(acc[r][1] + bb.y, 0.f);
      o.z = fmaxf(acc[r][2] + bb.z, 0.f);
      o.w = fmaxf(acc[r][3] + bb.w, 0.f);
      *(float4*)(H + (size_t)(tok0 + w * 64 + ty * 8 + r) * DH + n0 + tx * 4) = o;
    }
  }
}

// =================== score: softmax + top2 + lists (per 16 tokens) ===================
__launch_bounds__(256)
__global__ void score_kernel(const float* __restrict__ H,
                             const float* __restrict__ w2,
                             const float* __restrict__ b2,
                             float* __restrict__ out,
                             int* __restrict__ cnt,
                             float* __restrict__ usage,
                             float* __restrict__ wts,
                             int* __restrict__ lists) {
  __shared__ __align__(16) float hs[16][260];
  __shared__ __align__(16) float w2t[16][260];
  __shared__ float ps[16][NE];
  __shared__ float us[4][NE];
  int tid = threadIdx.x;
  int tok0 = blockIdx.x * 16;
  {
    int r = tid >> 4, seg = tid & 15;
    const float* hp = H + (size_t)(tok0 + r) * DH + seg * 16;
    *(float4*)&hs[r][seg * 16 + 0]  = *(const float4*)(hp + 0);
    *(float4*)&hs[r][seg * 16 + 4]  = *(const float4*)(hp + 4);
    *(float4*)&hs[r][seg * 16 + 8]  = *(const float4*)(hp + 8);
    *(float4*)&hs[r][seg * 16 + 12] = *(const float4*)(hp + 12);
  }
  {
    float4 a = *(const float4*)(w2 + (size_t)tid * 16 + 0);
    float4 b = *(const float4*)(w2 + (size_t)tid * 16 + 4);
    float4 c = *(const float4*)(w2 + (size_t)tid * 16 + 8);
    float4 d = *(const float4*)(w2 + (size_t)tid * 16 + 12);
    w2t[0][tid] = a.x;  w2t[1][tid] = a.y;  w2t[2][tid] = a.z;  w2t[3][tid] = a.w;
    w2t[4][tid] = b.x;  w2t[5][tid] = b.y;  w2t[6][tid] = b.z;  w2t[7][tid] = b.w;
    w2t[8][tid] = c.x;  w2t[9][tid] = c.y;  w2t[10][tid] = c.z; w2t[11][tid] = c.w;
    w2t[12][tid] = d.x; w2t[13][tid] = d.y; w2t[14][tid] = d.z; w2t[15][tid] = d.w;
  }
  __syncthreads();
  int t = tid >> 4, e = tid & 15;
  float s = b2[e];
#pragma unroll 4
  for (int j4 = 0; j4 < 64; ++j4) {
    float4 hv = *(const float4*)&hs[t][j4 * 4];
    float4 wv = *(const float4*)&w2t[e][j4 * 4];
    s = fmaf(hv.x, wv.x, fmaf(hv.y, wv.y, fmaf(hv.z, wv.z, fmaf(hv.w, wv.w, s))));
  }
  s *= TEMP_INV;
  float m = s;
#pragma unroll
  for (int d = 1; d < 16; d <<= 1) m = fmaxf(m, __shfl_xor(m, d));
  float p = expf(s - m);
  float sum = p;
#pragma unroll
  for (int d = 1; d < 16; d <<= 1) sum += __shfl_xor(sum, d);
  float prob = p / sum;
  out[OUT_PROBS + (size_t)(tok0 + t) * NE + e] = prob;
  ps[t][e] = prob;
  float v = prob;
  v += __shfl_xor(v, 16);
  v += __shfl_xor(v, 32);
  if ((tid & 63) < 16) us[tid >> 6][e] = v;
  __syncthreads();
  if (tid < 16) atomicAdd(&usage[tid], us[0][tid] + us[1][tid] + us[2][tid] + us[3][tid]);

  if (tid < 16) {
    int tt = tid;
    float v1 = -1.f; int i1 = 0;
    for (int ee = 0; ee < NE; ++ee) { float pv = ps[tt][ee]; if (pv > v1) { v1 = pv; i1 = ee; } }
    float v2 = -1.f; int i2 = 0;
    for (int ee = 0; ee < NE; ++ee) { if (ee == i1) continue; float pv = ps[tt][ee]; if (pv > v2) { v2 = pv; i2 = ee; } }
    float mm = fmaxf(v1, v2);
    float e0 = expf(v1 - mm), e1 = expf(v2 - mm);
    float rs = 1.f / (e0 + e1);
    int gt = tok0 + tt;
    wts[2 * gt]     = e0 * rs;
    wts[2 * gt + 1] = e1 * rs;
    int p1 = atomicAdd(&cnt[i1], 1);
    lists[i1 * CAP + p1] = 2 * gt;
    int p2 = atomicAdd(&cnt[i2], 1);
    lists[i2 * CAP + p2] = 2 * gt + 1;
  }
}

// =================== sched: tile descriptors + load-balance loss ===================
__global__ void sched_kernel(const int* __restrict__ cnt,
                             const float* __restrict__ usage,
                             int* __restrict__ ntiles,
                             int2* __restrict__ desc,
                             float* __restrict__ out_loss) {
  int lane = threadIdx.x;
  int e = lane & 15;
  int c = (lane < 16) ? cnt[e] : 0;
  int tl = (c + 127) >> 7;
  int v = tl;
#pragma unroll
  for (int d = 1; d < 16; d <<= 1) {
    int u = __shfl_up(v, d);
    if (lane >= d) v += u;
  }
  int excl = v - tl;
  int tot = __shfl(v, 15);
  if (lane == 0) *ntiles = tot;
  if (lane < 16) {
    for (int i = 0; i < tl; ++i) desc[excl + i] = make_int2(e, i << 7);
    float d0 = usage[e] * (1.f / 4096.f) - (1.f / 16.f);
    float ls = d0 * d0;
#pragma unroll
    for (int d = 1; d < 16; d <<= 1) ls += __shfl_xor(ls, d);
    if (lane == 0) *out_loss = ls * (1.f / 16.f);
  }
}

// =================== gather: build A bf16 chunk-major [ty][kc8][128][64], swizzled ===================
__launch_bounds__(256)
__global__ void gather_kernel(const float* __restrict__ x,
                              const int* __restrict__ cnt,
                              const int* __restrict__ ntiles,
                              const int2* __restrict__ desc,
                              const int* __restrict__ lists,
                              unsigned short* __restrict__ G) {
  int ty = blockIdx.x;
  if (ty >= *ntiles) return;
  int2 dd = desc[ty];
  int e = dd.x, i0 = dd.y;
  int cntE = cnt[e];
  int tid = threadIdx.x, r = tid >> 1, h = tid & 1;
  int aidx = i0 + r;
  bool valid = aidx < cntE;
  int slot = valid ? lists[e * CAP + aidx] : 0;
  const float* xrow = x + (size_t)(slot >> 1) * DIM;
  int chunk = blockIdx.y * 2 + h;
  unsigned short* dst = G + (size_t)ty * 65536 + (size_t)chunk * 8192 + r * 64;
  int sx = r & 7;
#pragma unroll
  for (int j = 0; j < 8; ++j) {
    u16x8 pk;
    if (valid) {
      float4 u = *(const float4*)(xrow + chunk * 64 + j * 8);
      float4 w = *(const float4*)(xrow + chunk * 64 + j * 8 + 4);
      pk[0] = f2bf(u.x); pk[1] = f2bf(u.y); pk[2] = f2bf(u.z); pk[3] = f2bf(u.w);
      pk[4] = f2bf(w.x); pk[5] = f2bf(w.y); pk[6] = f2bf(w.z); pk[7] = f2bf(w.w);
    } else {
      pk = u16x8{0, 0, 0, 0, 0, 0, 0, 0};
    }
    *(u16x8*)(dst + ((j ^ sx) << 3)) = pk;
  }
}

// =================== up GEMM: G @ Tup -> gelu(tanh) -> hid (bf16, swizzled granules) ===================
// BM=128 BN=128 BK=64, 4 waves (2x2), dbuf global_load_lds, 2-phase. XCD-chunked 1D grid.
__launch_bounds__(256)
__global__ void up_kernel(const unsigned short* __restrict__ G,
                          const unsigned short* __restrict__ Tup,
                          const float* __restrict__ up_b,
                          const int* __restrict__ ntiles,
                          const int2* __restrict__ desc,
                          unsigned short* __restrict__ hid) {
  int lid = (blockIdx.x & 7) * (MAXTILES * 16 / 8) + (blockIdx.x >> 3);
  int ty = lid >> 4, fb = lid & 15;
  if (ty >= *ntiles) return;
  int e = desc[ty].x;
  int f0 = fb * 128;
  __shared__ __align__(16) unsigned short smem[32768];   // 64KB: A0 A1 B0 B1 (8192 each)
  int tid = threadIdx.x, lane = tid & 63, wid = tid >> 6;
  const unsigned short* Asrc = G + (size_t)ty * 65536;                    // + kc*8192
  const unsigned short* Bsrc = Tup + ((size_t)(e * 8) * FF + f0) * 64;    // + kc*FF*64

  int wr = wid >> 1, wc = wid & 1, ln15 = lane & 15, lq = lane >> 4;
  f32x4 acc[4][4];
#pragma unroll
  for (int i = 0; i < 4; ++i)
#pragma unroll
    for (int j = 0; j < 4; ++j) acc[i][j] = f32x4{0.f, 0.f, 0.f, 0.f};

#define UP_STAGE(b, kc) do {                                          \
    const unsigned short* a_ = Asrc + (size_t)(kc) * 8192;            \
    const unsigned short* b_ = Bsrc + (size_t)(kc) * FF * 64;         \
    unsigned short* al_ = smem + (b) * 8192;                          \
    unsigned short* bl_ = smem + 16384 + (b) * 8192;                  \
    _Pragma("unroll")                                                 \
    for (int i_ = 0; i_ < 4; ++i_) {                                  \
      int off_ = (wid * 4 + i_) * 512;                                \
      GLOAD16(a_ + off_ + lane * 8, al_ + off_ + lane * 8);           \
      GLOAD16(b_ + off_ + lane * 8, bl_ + off_ + lane * 8);           \
    }                                                                 \
  } while (0)

  UP_STAGE(0, 0);
  asm volatile("s_waitcnt vmcnt(0)" ::: "memory");
  __syncthreads();
  int cur = 0;
  for (int kc = 0; kc < 8; ++kc) {
    if (kc < 7) UP_STAGE(cur ^ 1, kc + 1);
    const unsigned short* As = smem + cur * 8192;
    const unsigned short* Bs = smem + 16384 + cur * 8192;
#pragma unroll
    for (int ksub = 0; ksub < 2; ++ksub) {
      bf16x8 a[4], b[4];
      int g = (ksub << 2) + lq;
      int sw = (g ^ (ln15 & 7)) << 3;   // XOR-swizzled granule slot
#pragma unroll
      for (int mi = 0; mi < 4; ++mi)
        a[mi] = *(const bf16x8*)(As + ((wr << 6) + (mi << 4) + ln15) * 64 + sw);
#pragma unroll
      for (int ni = 0; ni < 4; ++ni)
        b[ni] = *(const bf16x8*)(Bs + ((wc << 6) + (ni << 4) + ln15) * 64 + sw);
#pragma unroll
      for (int mi = 0; mi < 4; ++mi)
#pragma unroll
        for (int ni = 0; ni < 4; ++ni)
          acc[mi][ni] = __builtin_amdgcn_mfma_f32_16x16x32_bf16(a[mi], b[ni], acc[mi][ni], 0, 0, 0);
    }
    asm volatile("s_waitcnt vmcnt(0)" ::: "memory");
    __syncthreads();
    cur ^= 1;
  }
  // epilogue: bias + tanh-gelu -> LDS transpose -> vectorized swizzled hid stores
  unsigned short* Cs = smem;  // [128][136] u16 (reuses A/B buffers)
#pragma unroll
  for (int mi = 0; mi < 4; ++mi) {
#pragma unroll
    for (int ni = 0; ni < 4; ++ni) {
      int col = (wc << 6) + (ni << 4) + ln15;
      float bias = up_b[e * FF + f0 + col];
#pragma unroll
      for (int q = 0; q < 4; ++q) {
        int row = (wr << 6) + (mi << 4) + (lq << 2) + q;
        float vv = acc[mi][ni][q] + bias;
        // gelu tanh-approx: x * sigmoid(2c(x + 0.044715x^3)), max dev ~3e-4
        float uu = vv * fmaf(vv * vv, 0.044715f, 1.0f) * 1.5957691216f; // 2*sqrt(2/pi)
        float gl = vv / (1.f + __expf(-uu));
        Cs[row * 136 + col] = f2bf(gl);
      }
    }
  }
  __syncthreads();
#pragma unroll
  for (int i = 0; i < 8; ++i) {
    int seg = tid + i * 256;
    int row = seg >> 4, c16 = seg & 15;
    int chunk = ty * 32 + (f0 >> 6) + (c16 >> 3);
    int slot = (c16 & 7) ^ (row & 7);
    u16x8 v = *(const u16x8*)(Cs + row * 136 + c16 * 8);
    *(u16x8*)(hid + ((size_t)chunk * 128 + row) * 64 + (slot << 3)) = v;
  }
#undef UP_STAGE
}

// =================== down GEMM: hid @ Tdn -> pairbuf (fp32 scatter) ===================
// BM=128 BN=64 BK=64, 4 waves (2x2), 32 k-chunks, 2-phase, 48KB LDS (~3 blk/CU).
// 1D grid (8*MAXTILES), XCD-chunked so all 8 n-blocks of a ty share an XCD.
__launch_bounds__(256)
__global__ void down_kernel(const unsigned short* __restrict__ hid,
                            const unsigned short* __restrict__ Tdn,
                            const float* __restrict__ down_b,
                            const int* __restrict__ cnt,
                            const int* __restrict__ ntiles,
                            const int2* __restrict__ desc,
                            const int* __restrict__ lists,
                            float* __restrict__ pairbuf) {
  int lid = (blockIdx.x & 7) * MAXTILES + (blockIdx.x >> 3);
  int ty = lid >> 3, nb = lid & 7;
  if (ty >= *ntiles) return;
  int2 dd = desc[ty];
  int e = dd.x, i0 = dd.y;
  int cntE = cnt[e];
  int n0 = nb * 64;
  __shared__ __align__(16) unsigned short smem[24576];   // A0 A1 (8192 u16) | B0 B1 (4096 u16)
  int tid = threadIdx.x, lane = tid & 63, wid = tid >> 6;
  const unsigned short* Asrc = hid + (size_t)ty * 32 * 8192;              // + kc*8192
  const unsigned short* Bsrc = Tdn + ((size_t)(e * 32) * DIM + n0) * 64;  // + kc*DIM*64

  int wr = wid >> 1, wc = wid & 1, ln15 = lane & 15, lq = lane >> 4;
  f32x4 acc[4][2];
#pragma unroll
  for (int i = 0; i < 4; ++i) { acc[i][0] = f32x4{0.f,0.f,0.f,0.f}; acc[i][1] = f32x4{0.f,0.f,0.f,0.f}; }

#define DN_STAGE(b, kc) do {                                          \
    const unsigned short* a_ = Asrc + (size_t)(kc) * 8192;            \
    const unsigned short* b_ = Bsrc + (size_t)(kc) * DIM * 64;        \
    unsigned short* al_ = smem + (b) * 8192;                          \
    unsigned short* bl_ = smem + 16384 + (b) * 4096;                  \
    _Pragma("unroll")                                                 \
    for (int i_ = 0; i_ < 4; ++i_) {                                  \
      int off_ = (wid * 4 + i_) * 512;                                \
      GLOAD16(a_ + off_ + lane * 8, al_ + off_ + lane * 8);           \
    }                                                                 \
    _Pragma("unroll")                                                 \
    for (int i_ = 0; i_ < 2; ++i_) {                                  \
      int off_ = (wid * 2 + i_) * 512;                                \
      GLOAD16(b_ + off_ + lane * 8, bl_ + off_ + lane * 8);           \
    }                                                                 \
  } while (0)

  DN_STAGE(0, 0);
  asm volatile("s_waitcnt vmcnt(0)" ::: "memory");
  __syncthreads();
  int cur = 0;
  for (int kc = 0; kc < 32; ++kc) {
    if (kc < 31) DN_STAGE(cur ^ 1, kc + 1);
    const unsigned short* As = smem + cur * 8192;
    const unsigned short* Bs = smem + 16384 + cur * 4096;
#pragma unroll
    for (int ksub = 0; ksub < 2; ++ksub) {
      bf16x8 a[4], b[2];
      int g = (ksub << 2) + lq;
      int sw = (g ^ (ln15 & 7)) << 3;
#pragma unroll
      for (int mi = 0; mi < 4; ++mi)
        a[mi] = *(const bf16x8*)(As + ((wr << 6) + (mi << 4) + ln15) * 64 + sw);
#pragma unroll
      for (int ni = 0; ni < 2; ++ni)
        b[ni] = *(const bf16x8*)(Bs + ((wc << 5) + (ni << 4) + ln15) * 64 + sw);
#pragma unroll
      for (int mi = 0; mi < 4; ++mi)
#pragma unroll
        for (int ni = 0; ni < 2; ++ni)
          acc[mi][ni] = __builtin_amdgcn_mfma_f32_16x16x32_bf16(a[mi], b[ni], acc[mi][ni], 0, 0, 0);
    }
    asm volatile("s_waitcnt vmcnt(0)" ::: "memory");
    __syncthreads();
    cur ^= 1;
  }
  // epilogue: bias + scatter rows via lists (64B-coalesced per quarter-wave)
#pragma unroll
  for (int mi = 0; mi < 4; ++mi) {
    int row = (wr << 6) + (mi << 4) + (lq << 2);
#pragma unroll
    for (int ni = 0; ni < 2; ++ni) {
      int col = n0 + (wc << 5) + (ni << 4) + ln15;
      float bias = down_b[e * DIM + col];
#pragma unroll
      for (int q = 0; q < 4; ++q) {
        int idx = i0 + row + q;
        if (idx < cntE) {
          int slot = lists[e * CAP + idx];
          pairbuf[(size_t)slot * DIM + col] = acc[mi][ni][q] + bias;
        }
      }
    }
  }
#undef DN_STAGE
}

// =================== combine: out[t] = w0*pair[2t] + w1*pair[2t+1] ===================
__launch_bounds__(256)
__global__ void combine_kernel(const float* __restrict__ pairbuf,
                               const float* __restrict__ wts,
                               float* __restrict__ out) {
  int idx = blockIdx.x * 256 + threadIdx.x;   // one float4 of output
  int t = idx >> 7, d4 = (idx & 127) << 2;
  float w0 = wts[2 * t], w1 = wts[2 * t + 1];
  float4 a = *(const float4*)(pairbuf + (size_t)(2 * t) * DIM + d4);
  float4 b = *(const float4*)(pairbuf + (size_t)(2 * t + 1) * DIM + d4);
  float4 r;
  r.x = w0 * a.x + w1 * b.x; r.y = w0 * a.y + w1 * b.y;
  r.z = w0 * a.z + w1 * b.z; r.w = w0 * a.w + w1 * b.w;
  *(float4*)(out + (size_t)t * DIM + d4) = r;
}

extern "C" void kernel_launch(void* const* d_in, const int* in_sizes, int n_in,
                              void* d_out, int out_size, void* d_ws, size_t ws_size,
                              hipStream_t stream) {
  (void)in_sizes; (void)n_in; (void)out_size; (void)ws_size;
  const float* x   = (const float*)d_in[0];
  const float* gw1 = (const float*)d_in[1];
  const float* gb1 = (const float*)d_in[2];
  const float* gw2 = (const float*)d_in[3];
  const float* gb2 = (const float*)d_in[4];
  const float* uw  = (const float*)d_in[5];
  const float* ub  = (const float*)d_in[6];
  const float* dw  = (const float*)d_in[7];
  const float* db  = (const float*)d_in[8];
  float* out = (float*)d_out;
  char* ws = (char*)d_ws;

  int*   cnt     = (int*)(ws + WS_CNT);
  float* usage   = (float*)(ws + WS_USAGE);
  int*   ntiles  = (int*)(ws + WS_NTILES);
  int2*  desc    = (int2*)(ws + WS_DESC);
  float* wts     = (float*)(ws + WS_WTS);
  int*   lists   = (int*)(ws + WS_LISTS);
  float* H       = (float*)(ws + WS_H);
  unsigned short* G   = (unsigned short*)(ws + WS_G);
  unsigned short* Tup = (unsigned short*)(ws + WS_TUP);
  unsigned short* Tdn = (unsigned short*)(ws + WS_TDN);
  unsigned short* hid = (unsigned short*)(ws + WS_HID);
  float* pairbuf = (float*)(ws + WS_PAIR);

  hipMemsetAsync(d_ws, 0, 1024, stream);  // zero cnt/usage/ntiles
  prep_kernel<<<2176, 256, 0, stream>>>(x, gw1, gb1, uw, dw, H, Tup, Tdn);
  score_kernel<<<NTOK / 16, 256, 0, stream>>>(H, gw2, gb2, out, cnt, usage, wts, lists);
  sched_kernel<<<1, 64, 0, stream>>>(cnt, usage, ntiles, desc, out + OUT_LOSS);
  gather_kernel<<<dim3(MAXTILES, 4), 256, 0, stream>>>(x, cnt, ntiles, desc, lists, G);
  up_kernel<<<16 * MAXTILES, 256, 0, stream>>>(G, Tup, ub, ntiles, desc, hid);
  down_kernel<<<8 * MAXTILES, 256, 0, stream>>>(hid, Tdn, db, cnt, ntiles, desc, lists, pairbuf);
  combine_kernel<<<NTOK * DIM / 4 / 256, 256, 0, stream>>>(pairbuf, wts, out);
}